// Round 18
// baseline (627.372 us; speedup 1.0000x reference)
//
#include <hip/hip_runtime.h>

#define NN 50000
#define EE 400000
#define MM 3
#define CHUNK 2048
#define NCHUNK ((NN + CHUNK - 1) / CHUNK)   // 25

typedef float f32x4 __attribute__((ext_vector_type(4)));
typedef short s16x8 __attribute__((ext_vector_type(8)));
typedef _Float16 half_t;
typedef _Float16 h16x4 __attribute__((ext_vector_type(4)));

union FU { float f; unsigned u; };

__device__ inline short bfhi(float x) {
    FU c; c.f = x;
    unsigned u = c.u;
    return (short)((u + 0x7fffu + ((u >> 16) & 1u)) >> 16);
}
__device__ inline float bf2f(short h) {
    FU c; c.u = ((unsigned)(unsigned short)h) << 16;
    return c.f;
}
__device__ inline float h2f(short bits) {
    union HU { short s; _Float16 h; } u; u.s = bits; return (float)u.h;
}

// ---------------- CSR build ----------------

__global__ __launch_bounds__(256) void init_kernel(int* counts, float* wsum) {
    int idx = blockIdx.x * 256 + threadIdx.x;
    if (idx < MM * NN) counts[idx] = 0;
    if (idx < MM) wsum[idx] = 0.0f;
}

__global__ __launch_bounds__(256) void hist_kernel(const int* __restrict__ dst,
                                                   int* __restrict__ counts) {
    int m = blockIdx.y;
    int e = blockIdx.x * 256 + threadIdx.x;
    if (e < EE) atomicAdd(&counts[m * NN + dst[m * EE + e]], 1);
}

__global__ __launch_bounds__(256) void scan_partial_kernel(const int* __restrict__ counts,
                                                           int* __restrict__ rp,
                                                           int* __restrict__ bsum) {
    int m = blockIdx.y, ch = blockIdx.x;
    const int* c = counts + m * NN;
    int* r = rp + m * (NN + 1);
    int t = threadIdx.x, lane = t & 63, wave = t >> 6;
    int i0 = ch * CHUNK + t * 8;
    int v[8]; int s = 0;
#pragma unroll
    for (int k = 0; k < 8; ++k) { int i = i0 + k; v[k] = (i < NN) ? c[i] : 0; s += v[k]; }
    int incl = s;
#pragma unroll
    for (int off = 1; off < 64; off <<= 1) {
        int u = __shfl_up(incl, off);
        if (lane >= off) incl += u;
    }
    int excl = incl - s;
    __shared__ int wsh[4];
    if (lane == 63) wsh[wave] = incl;
    __syncthreads();
    int woff = 0;
    for (int w = 0; w < wave; ++w) woff += wsh[w];
    int run = excl + woff;
#pragma unroll
    for (int k = 0; k < 8; ++k) { int i = i0 + k; if (i < NN) r[i] = run; run += v[k]; }
    if (t == 255) bsum[m * NCHUNK + ch] = woff + incl;
}

__global__ __launch_bounds__(256) void scan_top_kernel(int* __restrict__ bsum) {
    int wave = threadIdx.x >> 6, lane = threadIdx.x & 63;
    if (wave < MM) {
        int v = (lane < NCHUNK) ? bsum[wave * NCHUNK + lane] : 0;
        int incl = v;
#pragma unroll
        for (int off = 1; off < 64; off <<= 1) {
            int u = __shfl_up(incl, off);
            if (lane >= off) incl += u;
        }
        if (lane < NCHUNK) bsum[wave * NCHUNK + lane] = incl - v;
    }
}

__global__ __launch_bounds__(256) void scan_add_kernel(const int* __restrict__ bsum,
                                                       int* __restrict__ rp,
                                                       int* __restrict__ cur) {
    int m = blockIdx.y, ch = blockIdx.x;
    int off = bsum[m * NCHUNK + ch];
    int* r = rp + m * (NN + 1);
    int* q = cur + m * (NN + 1);
    int i0 = ch * CHUNK + threadIdx.x * 8;
#pragma unroll
    for (int k = 0; k < 8; ++k) {
        int i = i0 + k;
        if (i < NN) { int val = r[i] + off; r[i] = val; q[i] = val; }
    }
    if (ch == 0 && threadIdx.x == 0) r[NN] = EE;
}

// ---------------- weight transpose + split ----------------
// [6][256n][256k] W_gat, then [128n][256k] sem weights (64 W1 | 64 Wp).

#define WG_ELEMS (6 * 256 * 256)
#define W_TOT (WG_ELEMS + 128 * 256)

__global__ __launch_bounds__(256) void splitW_kernel(const float* __restrict__ Wg,
                                                     const float* __restrict__ W1,
                                                     const float* __restrict__ Wp,
                                                     short* __restrict__ Whi,
                                                     short* __restrict__ Wlo) {
    int idx = blockIdx.x * 256 + threadIdx.x;
    if (idx >= W_TOT) return;
    float v;
    if (idx < WG_ELEMS) {
        int mat = idx >> 16, rem = idx & 65535;
        int n = rem >> 8, k = rem & 255;
        v = Wg[mat * 65536 + k * 256 + n];
    } else {
        int i2 = idx - WG_ELEMS;
        int n = i2 >> 8, k = i2 & 255;
        v = (n < 64) ? W1[k * 64 + n] : Wp[k * 64 + n - 64];
    }
    short h = bfhi(v);
    Whi[idx] = h;
    Wlo[idx] = bfhi(v - bf2f(h));
}

// ---------------- GEMM core (r15-best): BM=64 x BN=256, 256 thr -----------

template<int AMODE>
__device__ __forceinline__ void gemm_core(
    int bx, int m,
    const float* __restrict__ Af, const half_t* __restrict__ A16,
    const short* __restrict__ Wthi, const short* __restrict__ Wtlo,
    half_t* __restrict__ featA,
    const float* __restrict__ alA, const float* __restrict__ arA,
    float* __restrict__ elA, float* __restrict__ erA) {
    __shared__ short Ah[64 * 32], Al[64 * 32], Bh[256 * 32], Bl[256 * 32];  // 40960 B
    const int t = threadIdx.x;
    const int lane = t & 63;
    const int wn = t >> 6;
    const int row0 = bx * 64;
    const float*  A0 = Af + (size_t)m * NN * 256;
    const short*  A1 = (const short*)(A16 + (size_t)m * NN * 256);
    const short*  Bgh = Wthi + (size_t)m * 65536;
    const short*  Bgl = Wtlo + (size_t)m * 65536;
    half_t* Ch = featA + (size_t)m * NN * 256;
    const float* al = alA + m * 256;
    const float* ar = arA + m * 256;
    float* el = elA + (size_t)m * NN * 4;
    float* er = erA + (size_t)m * NN * 4;
    f32x4 acc[4][4] = {};

    const int r = t >> 2, c0 = t & 3;
    const int aoff = r * 32 + ((c0 ^ ((r >> 1) & 3)) << 3);
    const int arow = row0 + r;
    const bool aval = (arow < NN);

    s16x8 praw = {0,0,0,0,0,0,0,0};
    float4 pf0 = make_float4(0.f,0.f,0.f,0.f), pf1 = make_float4(0.f,0.f,0.f,0.f);

    if (AMODE == 1) {
        if (aval) praw = *(const s16x8*)(A1 + (size_t)arow * 256 + c0 * 8);
    } else {
        if (aval) {
            pf0 = *(const float4*)(A0 + (size_t)arow * 256 + c0 * 8);
            pf1 = *(const float4*)(A0 + (size_t)arow * 256 + c0 * 8 + 4);
        }
    }

    for (int k0 = 0; k0 < 256; k0 += 32) {
        {
            float v[8];
            if (AMODE == 1) {
#pragma unroll
                for (int j = 0; j < 8; ++j) v[j] = h2f(praw[j]);
            } else {
                v[0] = pf0.x; v[1] = pf0.y; v[2] = pf0.z; v[3] = pf0.w;
                v[4] = pf1.x; v[5] = pf1.y; v[6] = pf1.z; v[7] = pf1.w;
            }
            s16x8 hh, ll;
#pragma unroll
            for (int j = 0; j < 8; ++j) {
                short hs = bfhi(v[j]);
                hh[j] = hs;
                ll[j] = bfhi(v[j] - bf2f(hs));
            }
            *(s16x8*)&Ah[aoff] = hh;
            *(s16x8*)&Al[aoff] = ll;
        }
#pragma unroll
        for (int u = 0; u < 4; ++u) {
            int n = u * 64 + (t >> 2), c = t & 3;
            s16x8 h = *(const s16x8*)(Bgh + (size_t)n * 256 + k0 + c * 8);
            s16x8 l = *(const s16x8*)(Bgl + (size_t)n * 256 + k0 + c * 8);
            int off = n * 32 + ((c ^ ((n >> 1) & 3)) << 3);
            *(s16x8*)&Bh[off] = h;
            *(s16x8*)&Bl[off] = l;
        }
        __syncthreads();
        if (k0 + 32 < 256) {
            if (AMODE == 1) {
                praw = s16x8{0,0,0,0,0,0,0,0};
                if (aval) praw = *(const s16x8*)(A1 + (size_t)arow * 256 + k0 + 32 + c0 * 8);
            } else {
                pf0 = make_float4(0.f,0.f,0.f,0.f); pf1 = make_float4(0.f,0.f,0.f,0.f);
                if (aval) {
                    pf0 = *(const float4*)(A0 + (size_t)arow * 256 + k0 + 32 + c0 * 8);
                    pf1 = *(const float4*)(A0 + (size_t)arow * 256 + k0 + 32 + c0 * 8 + 4);
                }
            }
        }
        int fr = lane & 15, ac = lane >> 4;
        s16x8 afh[4], afl[4], bfh[4], bfl[4];
#pragma unroll
        for (int i = 0; i < 4; ++i) {
            int rr = i * 16 + fr;
            int off = rr * 32 + ((ac ^ ((rr >> 1) & 3)) << 3);
            afh[i] = *(const s16x8*)&Ah[off];
            afl[i] = *(const s16x8*)&Al[off];
        }
#pragma unroll
        for (int j = 0; j < 4; ++j) {
            int n = wn * 64 + j * 16 + fr;
            int off = n * 32 + ((ac ^ ((n >> 1) & 3)) << 3);
            bfh[j] = *(const s16x8*)&Bh[off];
            bfl[j] = *(const s16x8*)&Bl[off];
        }
#pragma unroll
        for (int i = 0; i < 4; ++i)
#pragma unroll
            for (int j = 0; j < 4; ++j) {
                acc[i][j] = __builtin_amdgcn_mfma_f32_16x16x32_bf16(afh[i], bfh[j], acc[i][j], 0, 0, 0);
                acc[i][j] = __builtin_amdgcn_mfma_f32_16x16x32_bf16(afh[i], bfl[j], acc[i][j], 0, 0, 0);
                acc[i][j] = __builtin_amdgcn_mfma_f32_16x16x32_bf16(afl[i], bfh[j], acc[i][j], 0, 0, 0);
            }
        __syncthreads();
    }

#pragma unroll
    for (int i = 0; i < 4; ++i) {
        int rbase = row0 + i * 16 + (lane >> 4) * 4;
#pragma unroll
        for (int j = 0; j < 4; ++j) {
            int col = wn * 64 + j * 16 + (lane & 15);
#pragma unroll
            for (int q = 0; q < 4; ++q) {
                int row = rbase + q;
                if (row < NN) Ch[(size_t)row * 256 + col] = (half_t)acc[i][j][q];
            }
        }
    }
    float alv[4], arv[4];
#pragma unroll
    for (int j = 0; j < 4; ++j) {
        int col = wn * 64 + j * 16 + (lane & 15);
        alv[j] = al[col];
        arv[j] = ar[col];
    }
#pragma unroll
    for (int i = 0; i < 4; ++i)
#pragma unroll
        for (int q = 0; q < 4; ++q) {
            float ep = acc[i][0][q] * alv[0] + acc[i][1][q] * alv[1]
                     + acc[i][2][q] * alv[2] + acc[i][3][q] * alv[3];
            float rp_ = acc[i][0][q] * arv[0] + acc[i][1][q] * arv[1]
                      + acc[i][2][q] * arv[2] + acc[i][3][q] * arv[3];
#pragma unroll
            for (int msk = 1; msk < 16; msk <<= 1) {
                ep += __shfl_xor(ep, msk);
                rp_ += __shfl_xor(rp_, msk);
            }
            if ((lane & 15) == 0) {
                int row = row0 + i * 16 + (lane >> 4) * 4 + q;
                if (row < NN) {
                    el[row * 4 + wn] = ep;
                    er[row * 4 + wn] = rp_;
                }
            }
        }
}

// ---------------- fused layer-0 GEMM + edge scatter ----------------

__global__ __launch_bounds__(256) void gemm0_scatter_kernel(
    const float* __restrict__ x,
    const short* __restrict__ Wthi, const short* __restrict__ Wtlo,
    half_t* __restrict__ featA,
    const float* __restrict__ alA, const float* __restrict__ arA,
    float* __restrict__ elA, float* __restrict__ erA,
    const int* __restrict__ src, const int* __restrict__ dst,
    int* __restrict__ cursor, long long* __restrict__ spair,
    int rowTiles) {
    const int m = blockIdx.y;
    if ((int)blockIdx.x < rowTiles) {
        gemm_core<0>(blockIdx.x, m, x, nullptr, Wthi, Wtlo, featA, alA, arA, elA, erA);
    } else {
        int e = (blockIdx.x - rowTiles) * 256 + threadIdx.x;
        if (e < EE) {
            int d = dst[m * EE + e];
            int pos = atomicAdd(&cursor[m * (NN + 1) + d], 1);
            long long p = ((long long)d << 32) | (unsigned)src[m * EE + e];
            __builtin_nontemporal_store(p, &spair[(size_t)m * EE + pos]);
        }
    }
}

__global__ __launch_bounds__(256) void mfma_gemm1_kernel(
    const half_t* __restrict__ Hb,
    const short* __restrict__ Wthi, const short* __restrict__ Wtlo,
    half_t* __restrict__ featA,
    const float* __restrict__ alA, const float* __restrict__ arA,
    float* __restrict__ elA, float* __restrict__ erA) {
    gemm_core<1>(blockIdx.x, blockIdx.y, nullptr, Hb, Wthi, Wtlo, featA, alA, arA, elA, erA);
}

// ---------------- semantic GEMM: BM=128 x BN=128, fp16 A (unchanged) -------

__global__ __launch_bounds__(256) void sem_gemm(
    const half_t* __restrict__ A16,
    const short* __restrict__ Wthi, const short* __restrict__ Wtlo,
    float* __restrict__ P,
    const float* __restrict__ b1, const float* __restrict__ w2,
    float* __restrict__ wsum,
    int nrows) {
    __shared__ short Ah[128 * 32], Al[128 * 32], Bh[128 * 32], Bl[128 * 32]; // 32 KB
    const int t = threadIdx.x;
    const int lane = t & 63;
    const int wave = t >> 6;
    const int wm = wave >> 1, wn = wave & 1;
    const int row0 = blockIdx.x * 128;
    const short* A1 = (const short*)A16;
    f32x4 acc[4][4] = {};

    const int r0 = (t * 2) >> 2, c0 = (t * 2) & 3;
    const int r1 = (t * 2 + 1) >> 2, c1 = (t * 2 + 1) & 3;
    const int aoff0 = r0 * 32 + ((c0 ^ ((r0 >> 1) & 3)) << 3);
    const int aoff1 = r1 * 32 + ((c1 ^ ((r1 >> 1) & 3)) << 3);
    const int arow0 = row0 + r0, arow1 = row0 + r1;

    s16x8 p0 = {0,0,0,0,0,0,0,0}, p1 = {0,0,0,0,0,0,0,0};
    if (arow0 < nrows) p0 = *(const s16x8*)(A1 + (size_t)arow0 * 256 + c0 * 8);
    if (arow1 < nrows) p1 = *(const s16x8*)(A1 + (size_t)arow1 * 256 + c1 * 8);

    for (int k0 = 0; k0 < 256; k0 += 32) {
        {
            s16x8 hh, ll;
#pragma unroll
            for (int j = 0; j < 8; ++j) {
                float v = h2f(p0[j]);
                short hs = bfhi(v);
                hh[j] = hs; ll[j] = bfhi(v - bf2f(hs));
            }
            *(s16x8*)&Ah[aoff0] = hh; *(s16x8*)&Al[aoff0] = ll;
#pragma unroll
            for (int j = 0; j < 8; ++j) {
                float v = h2f(p1[j]);
                short hs = bfhi(v);
                hh[j] = hs; ll[j] = bfhi(v - bf2f(hs));
            }
            *(s16x8*)&Ah[aoff1] = hh; *(s16x8*)&Al[aoff1] = ll;
        }
#pragma unroll
        for (int u = 0; u < 2; ++u) {
            int idx = t * 2 + u;
            int n = idx >> 2, c = idx & 3;
            s16x8 h = *(const s16x8*)(Wthi + (size_t)n * 256 + k0 + c * 8);
            s16x8 l = *(const s16x8*)(Wtlo + (size_t)n * 256 + k0 + c * 8);
            int off = n * 32 + ((c ^ ((n >> 1) & 3)) << 3);
            *(s16x8*)&Bh[off] = h;
            *(s16x8*)&Bl[off] = l;
        }
        __syncthreads();
        if (k0 + 32 < 256) {
            p0 = s16x8{0,0,0,0,0,0,0,0}; p1 = s16x8{0,0,0,0,0,0,0,0};
            if (arow0 < nrows) p0 = *(const s16x8*)(A1 + (size_t)arow0 * 256 + k0 + 32 + c0 * 8);
            if (arow1 < nrows) p1 = *(const s16x8*)(A1 + (size_t)arow1 * 256 + k0 + 32 + c1 * 8);
        }
        int fr = lane & 15, ac = lane >> 4;
        s16x8 afh[4], afl[4], bfh[4], bfl[4];
#pragma unroll
        for (int i = 0; i < 4; ++i) {
            int rr = wm * 64 + i * 16 + fr;
            int off = rr * 32 + ((ac ^ ((rr >> 1) & 3)) << 3);
            afh[i] = *(const s16x8*)&Ah[off];
            afl[i] = *(const s16x8*)&Al[off];
        }
#pragma unroll
        for (int j = 0; j < 4; ++j) {
            int n = wn * 64 + j * 16 + fr;
            int off = n * 32 + ((ac ^ ((n >> 1) & 3)) << 3);
            bfh[j] = *(const s16x8*)&Bh[off];
            bfl[j] = *(const s16x8*)&Bl[off];
        }
#pragma unroll
        for (int i = 0; i < 4; ++i)
#pragma unroll
            for (int j = 0; j < 4; ++j) {
                acc[i][j] = __builtin_amdgcn_mfma_f32_16x16x32_bf16(afh[i], bfh[j], acc[i][j], 0, 0, 0);
                acc[i][j] = __builtin_amdgcn_mfma_f32_16x16x32_bf16(afh[i], bfl[j], acc[i][j], 0, 0, 0);
                acc[i][j] = __builtin_amdgcn_mfma_f32_16x16x32_bf16(afl[i], bfh[j], acc[i][j], 0, 0, 0);
            }
        __syncthreads();
    }

    float* wp = (float*)&Ah[0];
    if (t < 3) wp[t] = 0.f;
    __syncthreads();
    int fr = lane & 15, ac = lane >> 4;
    if (wn == 0) {
        float b1v[4], w2v[4];
#pragma unroll
        for (int j = 0; j < 4; ++j) {
            int col = j * 16 + fr;
            b1v[j] = b1[col];
            w2v[j] = w2[col];
        }
#pragma unroll
        for (int i = 0; i < 4; ++i)
#pragma unroll
            for (int q = 0; q < 4; ++q) {
                float ep = tanhf(acc[i][0][q] + b1v[0]) * w2v[0]
                         + tanhf(acc[i][1][q] + b1v[1]) * w2v[1]
                         + tanhf(acc[i][2][q] + b1v[2]) * w2v[2]
                         + tanhf(acc[i][3][q] + b1v[3]) * w2v[3];
#pragma unroll
                for (int msk = 1; msk < 16; msk <<= 1) ep += __shfl_xor(ep, msk);
                if (fr == 0) {
                    int row = row0 + wm * 64 + i * 16 + ac * 4 + q;
                    if (row < nrows) atomicAdd(&wp[row / NN], ep);
                }
            }
    } else {
#pragma unroll
        for (int i = 0; i < 4; ++i) {
            int rbase = row0 + wm * 64 + i * 16 + ac * 4;
#pragma unroll
            for (int j = 0; j < 4; ++j) {
                int pcol = j * 16 + fr;
#pragma unroll
                for (int q = 0; q < 4; ++q) {
                    int row = rbase + q;
                    if (row < nrows) P[(size_t)row * 64 + pcol] = acc[i][j][q];
                }
            }
        }
    }
    __syncthreads();
    if (t < 3) atomicAdd(&wsum[t], wp[t]);
}

// ---------------- edge-softmax aggregation ----------------
// Predicated 8-wide edge groups: every node processed as ceil(deg/8)
// straight-line groups of 8 independent predicated edges (OOB edges clamp
// to beg, weight x0) -> 8 gathers in flight, no serial scalar tail.

__global__ __launch_bounds__(256) void agg_edges_kernel(const half_t* __restrict__ featA,
                                                        const float* __restrict__ elA,
                                                        const float* __restrict__ erA,
                                                        const int* __restrict__ row_ptrA,
                                                        const long long* __restrict__ spairA,
                                                        const float* __restrict__ biasL,
                                                        half_t* __restrict__ HbA) {
    const int m = blockIdx.y;
    const half_t* feat = featA + (size_t)m * NN * 256;
    const float* el = elA + (size_t)m * NN * 4;
    const float* er = erA + (size_t)m * NN * 4;
    const int* row_ptr = row_ptrA + (size_t)m * (NN + 1);
    const long long* spair = spairA + (size_t)m * EE;
    const float* bias = biasL + m * 256;
    half_t* out = HbA + (size_t)m * NN * 256;

    int wave = threadIdx.x >> 6;
    int lane = threadIdx.x & 63;
    int n = blockIdx.x * 4 + wave;
    int h = lane >> 4;
    int beg = row_ptr[n], end = row_ptr[n + 1];
    float ern = er[n * 4 + h];
    const h16x4* fb = (const h16x4*)feat + lane;
    float a0[8] = {}, a1[8] = {}, a2[8] = {}, a3[8] = {}, dd[8] = {};

    for (int j = beg; j < end; j += 8) {
        int idxk[8];
        float mk[8];
#pragma unroll
        for (int k = 0; k < 8; ++k) {
            bool v = (j + k) < end;
            idxk[k] = v ? (j + k) : beg;
            mk[k] = v ? 1.f : 0.f;
        }
        int sk[8];
#pragma unroll
        for (int k = 0; k < 8; ++k) sk[k] = (int)(unsigned)spair[idxk[k]];
        float wk[8];
#pragma unroll
        for (int k = 0; k < 8; ++k) {
            float e = el[sk[k] * 4 + h] + ern;
            e = e > 0.f ? e : 0.2f * e;
            wk[k] = __expf(e) * mk[k];
        }
        h16x4 fk[8];
#pragma unroll
        for (int k = 0; k < 8; ++k) fk[k] = fb[(size_t)sk[k] * 64];
#pragma unroll
        for (int k = 0; k < 8; ++k) {
            a0[k] = fmaf(wk[k], (float)fk[k].x, a0[k]);
            a1[k] = fmaf(wk[k], (float)fk[k].y, a1[k]);
            a2[k] = fmaf(wk[k], (float)fk[k].z, a2[k]);
            a3[k] = fmaf(wk[k], (float)fk[k].w, a3[k]);
            dd[k] += wk[k];
        }
    }
    float den = (((dd[0] + dd[1]) + (dd[2] + dd[3])) + ((dd[4] + dd[5]) + (dd[6] + dd[7])));
    den = fmaxf(den, 1e-9f);
    float s0 = (((a0[0] + a0[1]) + (a0[2] + a0[3])) + ((a0[4] + a0[5]) + (a0[6] + a0[7])));
    float s1 = (((a1[0] + a1[1]) + (a1[2] + a1[3])) + ((a1[4] + a1[5]) + (a1[6] + a1[7])));
    float s2 = (((a2[0] + a2[1]) + (a2[2] + a2[3])) + ((a2[4] + a2[5]) + (a2[6] + a2[7])));
    float s3 = (((a3[0] + a3[1]) + (a3[2] + a3[3])) + ((a3[4] + a3[5]) + (a3[6] + a3[7])));
    int col = lane * 4;
    float o0 = s0 / den + bias[col + 0];
    float o1 = s1 / den + bias[col + 1];
    float o2 = s2 / den + bias[col + 2];
    float o3 = s3 / den + bias[col + 3];
    o0 = o0 > 0.f ? o0 : __expf(o0) - 1.0f;
    o1 = o1 > 0.f ? o1 : __expf(o1) - 1.0f;
    o2 = o2 > 0.f ? o2 : __expf(o2) - 1.0f;
    o3 = o3 > 0.f ? o3 : __expf(o3) - 1.0f;
    h16x4 ov; ov.x = (half_t)o0; ov.y = (half_t)o1; ov.z = (half_t)o2; ov.w = (half_t)o3;
    ((h16x4*)(out + (size_t)n * 256))[lane] = ov;
}

// ---------------- beta + final combine ----------------

__global__ void beta_kernel(const float* __restrict__ wsum, float* __restrict__ beta) {
    if (threadIdx.x == 0 && blockIdx.x == 0) {
        float w0 = wsum[0] / (float)NN, w1 = wsum[1] / (float)NN, w2 = wsum[2] / (float)NN;
        float mx = fmaxf(w0, fmaxf(w1, w2));
        float e0 = __expf(w0 - mx), e1 = __expf(w1 - mx), e2 = __expf(w2 - mx);
        float s = e0 + e1 + e2;
        beta[0] = e0 / s; beta[1] = e1 / s; beta[2] = e2 / s;
    }
}

__global__ __launch_bounds__(256) void combine_out_kernel(const float* __restrict__ P,
                                                          const float* __restrict__ beta,
                                                          const float* __restrict__ bp,
                                                          float* __restrict__ out) {
    int idx4 = blockIdx.x * 256 + threadIdx.x;
    if (idx4 >= NN * 64 / 4) return;
    float b0 = beta[0], b1 = beta[1], b2 = beta[2];
    float4 p0 = ((const float4*)P)[idx4];
    float4 p1 = ((const float4*)P)[idx4 + NN * 16];
    float4 p2 = ((const float4*)P)[idx4 + NN * 32];
    float4 bpv = *(const float4*)(bp + ((idx4 * 4) & 63));
    float4 o;
    o.x = b0 * p0.x + b1 * p1.x + b2 * p2.x + bpv.x;
    o.y = b0 * p0.y + b1 * p1.y + b2 * p2.y + bpv.y;
    o.z = b0 * p0.z + b1 * p1.z + b2 * p2.z + bpv.z;
    o.w = b0 * p0.w + b1 * p1.w + b2 * p2.w + bpv.w;
    ((float4*)out)[idx4] = o;
}

// ---------------- host launch ----------------

extern "C" void kernel_launch(void* const* d_in, const int* in_sizes, int n_in,
                              void* d_out, int out_size, void* d_ws, size_t ws_size,
                              hipStream_t stream) {
    const float* x        = (const float*)d_in[0];
    const float* W_gat    = (const float*)d_in[1];
    const float* attn_l   = (const float*)d_in[2];
    const float* attn_r   = (const float*)d_in[3];
    const float* bias_gat = (const float*)d_in[4];
    const float* W1       = (const float*)d_in[5];
    const float* b1       = (const float*)d_in[6];
    const float* W2       = (const float*)d_in[7];
    const float* Wp       = (const float*)d_in[8];
    const float* bp       = (const float*)d_in[9];
    const int*   src      = (const int*)d_in[10];
    const int*   dst      = (const int*)d_in[11];
    float* out = (float*)d_out;

    char* ws = (char*)d_ws;
    size_t off = 0;
    auto alloc = [&](size_t bytes) { size_t o = off; off = (off + bytes + 255) & ~(size_t)255; return o; };
    half_t* Hb      = (half_t*)(ws + alloc((size_t)MM * NN * 256 * 2));
    half_t* feat    = (half_t*)(ws + alloc((size_t)MM * NN * 256 * 2));
    float*  P       = (float*)(ws + alloc((size_t)MM * NN * 64 * 4));
    float*  el      = (float*)(ws + alloc((size_t)MM * NN * 4 * 4));
    float*  er      = (float*)(ws + alloc((size_t)MM * NN * 4 * 4));
    int*    counts  = (int*)(ws + alloc((size_t)MM * NN * 4));
    int*    row_ptr = (int*)(ws + alloc((size_t)MM * (NN + 1) * 4));
    int*    cursor  = (int*)(ws + alloc((size_t)MM * (NN + 1) * 4));
    long long* spair = (long long*)(ws + alloc((size_t)MM * EE * 8));
    int*    bsum    = (int*)(ws + alloc((size_t)MM * NCHUNK * 4));
    short*  Whi     = (short*)(ws + alloc((size_t)W_TOT * 2));
    short*  Wlo     = (short*)(ws + alloc((size_t)W_TOT * 2));
    float*  wsum    = (float*)(ws + alloc(16));
    float*  beta    = (float*)(ws + alloc(16));

    init_kernel<<<dim3((MM * NN + 255) / 256), 256, 0, stream>>>(counts, wsum);
    hist_kernel<<<dim3((EE + 255) / 256, MM), 256, 0, stream>>>(dst, counts);
    scan_partial_kernel<<<dim3(NCHUNK, MM), 256, 0, stream>>>(counts, row_ptr, bsum);
    scan_top_kernel<<<dim3(1), 256, 0, stream>>>(bsum);
    scan_add_kernel<<<dim3(NCHUNK, MM), 256, 0, stream>>>(bsum, row_ptr, cursor);
    splitW_kernel<<<dim3((W_TOT + 255) / 256), 256, 0, stream>>>(W_gat, W1, Wp, Whi, Wlo);

    const int rowTiles = (NN + 63) / 64;           // 782
    const int scatBlocks = (EE + 255) / 256;       // 1563

    // layer 0: fused GEMM<0> + scatter (independent work, co-dispatched)
    gemm0_scatter_kernel<<<dim3(rowTiles + scatBlocks, MM), 256, 0, stream>>>(
        x, Whi, Wlo, feat, attn_l, attn_r, el, er,
        src, dst, cursor, spair, rowTiles);
    agg_edges_kernel<<<dim3(NN / 4, MM), 256, 0, stream>>>(
        feat, el, er, row_ptr, spair, bias_gat, Hb);

    // layer 1
    mfma_gemm1_kernel<<<dim3(rowTiles, MM), 256, 0, stream>>>(
        Hb, Whi + (size_t)MM * 65536, Wlo + (size_t)MM * 65536,
        feat, attn_l + (size_t)MM * 256, attn_r + (size_t)MM * 256, el, er);
    agg_edges_kernel<<<dim3(NN / 4, MM), 256, 0, stream>>>(
        feat, el, er, row_ptr, spair, bias_gat + (size_t)MM * 256, Hb);

    // merged semantic + projection pass over all 3 metapaths (Hb contiguous)
    sem_gemm<<<dim3((MM * NN + 127) / 128), 256, 0, stream>>>(
        Hb, Whi + WG_ELEMS, Wlo + WG_ELEMS, P, b1, W2, wsum, MM * NN);
    beta_kernel<<<dim3(1), 64, 0, stream>>>(wsum, beta);
    combine_out_kernel<<<dim3((NN * 16 + 255) / 256), 256, 0, stream>>>(P, beta, bp, out);
}

// Round 19
// 573.327 us; speedup vs baseline: 1.0943x; 1.0943x over previous
//
#include <hip/hip_runtime.h>

#define NN 50000
#define EE 400000
#define MM 3
#define CHUNK 2048
#define NCHUNK ((NN + CHUNK - 1) / CHUNK)   // 25

typedef float f32x4 __attribute__((ext_vector_type(4)));
typedef short s16x8 __attribute__((ext_vector_type(8)));
typedef _Float16 half_t;
typedef _Float16 h16x4 __attribute__((ext_vector_type(4)));

union FU { float f; unsigned u; };

__device__ inline short bfhi(float x) {
    FU c; c.f = x;
    unsigned u = c.u;
    return (short)((u + 0x7fffu + ((u >> 16) & 1u)) >> 16);
}
__device__ inline float bf2f(short h) {
    FU c; c.u = ((unsigned)(unsigned short)h) << 16;
    return c.f;
}
__device__ inline float h2f(short bits) {
    union HU { short s; _Float16 h; } u; u.s = bits; return (float)u.h;
}

// ---------------- CSR build ----------------

__global__ __launch_bounds__(256) void init_kernel(int* counts, float* wsum) {
    int idx = blockIdx.x * 256 + threadIdx.x;
    if (idx < MM * NN) counts[idx] = 0;
    if (idx < MM) wsum[idx] = 0.0f;
}

#define WG_ELEMS (6 * 256 * 256)
#define W_TOT (WG_ELEMS + 128 * 256)
#define SPLITW_BLOCKS ((W_TOT + 255) / 256)             // 1664
#define SPLITW_PER_Y ((SPLITW_BLOCKS + MM - 1) / MM)    // 555

// hist (per-metapath) co-dispatched with splitW (independent work).
__global__ __launch_bounds__(256) void hist_splitW_kernel(
    const int* __restrict__ dst, int* __restrict__ counts,
    const float* __restrict__ Wg, const float* __restrict__ W1,
    const float* __restrict__ Wp,
    short* __restrict__ Whi, short* __restrict__ Wlo, int histBlocks) {
    const int m = blockIdx.y;
    if ((int)blockIdx.x < histBlocks) {
        int e = blockIdx.x * 256 + threadIdx.x;
        if (e < EE) atomicAdd(&counts[m * NN + dst[m * EE + e]], 1);
    } else {
        int b = ((int)blockIdx.x - histBlocks) * MM + m;
        int idx = b * 256 + threadIdx.x;
        if (idx >= W_TOT) return;
        float v;
        if (idx < WG_ELEMS) {
            int mat = idx >> 16, rem = idx & 65535;
            int n = rem >> 8, k = rem & 255;
            v = Wg[mat * 65536 + k * 256 + n];
        } else {
            int i2 = idx - WG_ELEMS;
            int n = i2 >> 8, k = i2 & 255;
            v = (n < 64) ? W1[k * 64 + n] : Wp[k * 64 + n - 64];
        }
        short h = bfhi(v);
        Whi[idx] = h;
        Wlo[idx] = bfhi(v - bf2f(h));
    }
}

__global__ __launch_bounds__(256) void scan_partial_kernel(const int* __restrict__ counts,
                                                           int* __restrict__ rp,
                                                           int* __restrict__ bsum) {
    int m = blockIdx.y, ch = blockIdx.x;
    const int* c = counts + m * NN;
    int* r = rp + m * (NN + 1);
    int t = threadIdx.x, lane = t & 63, wave = t >> 6;
    int i0 = ch * CHUNK + t * 8;
    int v[8]; int s = 0;
#pragma unroll
    for (int k = 0; k < 8; ++k) { int i = i0 + k; v[k] = (i < NN) ? c[i] : 0; s += v[k]; }
    int incl = s;
#pragma unroll
    for (int off = 1; off < 64; off <<= 1) {
        int u = __shfl_up(incl, off);
        if (lane >= off) incl += u;
    }
    int excl = incl - s;
    __shared__ int wsh[4];
    if (lane == 63) wsh[wave] = incl;
    __syncthreads();
    int woff = 0;
    for (int w = 0; w < wave; ++w) woff += wsh[w];
    int run = excl + woff;
#pragma unroll
    for (int k = 0; k < 8; ++k) { int i = i0 + k; if (i < NN) r[i] = run; run += v[k]; }
    if (t == 255) bsum[m * NCHUNK + ch] = woff + incl;
}

__global__ __launch_bounds__(256) void scan_top_kernel(int* __restrict__ bsum) {
    int wave = threadIdx.x >> 6, lane = threadIdx.x & 63;
    if (wave < MM) {
        int v = (lane < NCHUNK) ? bsum[wave * NCHUNK + lane] : 0;
        int incl = v;
#pragma unroll
        for (int off = 1; off < 64; off <<= 1) {
            int u = __shfl_up(incl, off);
            if (lane >= off) incl += u;
        }
        if (lane < NCHUNK) bsum[wave * NCHUNK + lane] = incl - v;
    }
}

__global__ __launch_bounds__(256) void scan_add_kernel(const int* __restrict__ bsum,
                                                       int* __restrict__ rp,
                                                       int* __restrict__ cur) {
    int m = blockIdx.y, ch = blockIdx.x;
    int off = bsum[m * NCHUNK + ch];
    int* r = rp + m * (NN + 1);
    int* q = cur + m * (NN + 1);
    int i0 = ch * CHUNK + threadIdx.x * 8;
#pragma unroll
    for (int k = 0; k < 8; ++k) {
        int i = i0 + k;
        if (i < NN) { int val = r[i] + off; r[i] = val; q[i] = val; }
    }
    if (ch == 0 && threadIdx.x == 0) r[NN] = EE;
}

// ---------------- GEMM core (r15-best): BM=64 x BN=256, 256 thr -----------

template<int AMODE>
__device__ __forceinline__ void gemm_core(
    int bx, int m,
    const float* __restrict__ Af, const half_t* __restrict__ A16,
    const short* __restrict__ Wthi, const short* __restrict__ Wtlo,
    half_t* __restrict__ featA,
    const float* __restrict__ alA, const float* __restrict__ arA,
    float* __restrict__ elA, float* __restrict__ erA) {
    __shared__ short Ah[64 * 32], Al[64 * 32], Bh[256 * 32], Bl[256 * 32];  // 40960 B
    const int t = threadIdx.x;
    const int lane = t & 63;
    const int wn = t >> 6;
    const int row0 = bx * 64;
    const float*  A0 = Af + (size_t)m * NN * 256;
    const short*  A1 = (const short*)(A16 + (size_t)m * NN * 256);
    const short*  Bgh = Wthi + (size_t)m * 65536;
    const short*  Bgl = Wtlo + (size_t)m * 65536;
    half_t* Ch = featA + (size_t)m * NN * 256;
    const float* al = alA + m * 256;
    const float* ar = arA + m * 256;
    float* el = elA + (size_t)m * NN * 4;
    float* er = erA + (size_t)m * NN * 4;
    f32x4 acc[4][4] = {};

    const int r = t >> 2, c0 = t & 3;
    const int aoff = r * 32 + ((c0 ^ ((r >> 1) & 3)) << 3);
    const int arow = row0 + r;
    const bool aval = (arow < NN);

    s16x8 praw = {0,0,0,0,0,0,0,0};
    float4 pf0 = make_float4(0.f,0.f,0.f,0.f), pf1 = make_float4(0.f,0.f,0.f,0.f);

    if (AMODE == 1) {
        if (aval) praw = *(const s16x8*)(A1 + (size_t)arow * 256 + c0 * 8);
    } else {
        if (aval) {
            pf0 = *(const float4*)(A0 + (size_t)arow * 256 + c0 * 8);
            pf1 = *(const float4*)(A0 + (size_t)arow * 256 + c0 * 8 + 4);
        }
    }

    for (int k0 = 0; k0 < 256; k0 += 32) {
        {
            float v[8];
            if (AMODE == 1) {
#pragma unroll
                for (int j = 0; j < 8; ++j) v[j] = h2f(praw[j]);
            } else {
                v[0] = pf0.x; v[1] = pf0.y; v[2] = pf0.z; v[3] = pf0.w;
                v[4] = pf1.x; v[5] = pf1.y; v[6] = pf1.z; v[7] = pf1.w;
            }
            s16x8 hh, ll;
#pragma unroll
            for (int j = 0; j < 8; ++j) {
                short hs = bfhi(v[j]);
                hh[j] = hs;
                ll[j] = bfhi(v[j] - bf2f(hs));
            }
            *(s16x8*)&Ah[aoff] = hh;
            *(s16x8*)&Al[aoff] = ll;
        }
#pragma unroll
        for (int u = 0; u < 4; ++u) {
            int n = u * 64 + (t >> 2), c = t & 3;
            s16x8 h = *(const s16x8*)(Bgh + (size_t)n * 256 + k0 + c * 8);
            s16x8 l = *(const s16x8*)(Bgl + (size_t)n * 256 + k0 + c * 8);
            int off = n * 32 + ((c ^ ((n >> 1) & 3)) << 3);
            *(s16x8*)&Bh[off] = h;
            *(s16x8*)&Bl[off] = l;
        }
        __syncthreads();
        if (k0 + 32 < 256) {
            if (AMODE == 1) {
                praw = s16x8{0,0,0,0,0,0,0,0};
                if (aval) praw = *(const s16x8*)(A1 + (size_t)arow * 256 + k0 + 32 + c0 * 8);
            } else {
                pf0 = make_float4(0.f,0.f,0.f,0.f); pf1 = make_float4(0.f,0.f,0.f,0.f);
                if (aval) {
                    pf0 = *(const float4*)(A0 + (size_t)arow * 256 + k0 + 32 + c0 * 8);
                    pf1 = *(const float4*)(A0 + (size_t)arow * 256 + k0 + 32 + c0 * 8 + 4);
                }
            }
        }
        int fr = lane & 15, ac = lane >> 4;
        s16x8 afh[4], afl[4], bfh[4], bfl[4];
#pragma unroll
        for (int i = 0; i < 4; ++i) {
            int rr = i * 16 + fr;
            int off = rr * 32 + ((ac ^ ((rr >> 1) & 3)) << 3);
            afh[i] = *(const s16x8*)&Ah[off];
            afl[i] = *(const s16x8*)&Al[off];
        }
#pragma unroll
        for (int j = 0; j < 4; ++j) {
            int n = wn * 64 + j * 16 + fr;
            int off = n * 32 + ((ac ^ ((n >> 1) & 3)) << 3);
            bfh[j] = *(const s16x8*)&Bh[off];
            bfl[j] = *(const s16x8*)&Bl[off];
        }
#pragma unroll
        for (int i = 0; i < 4; ++i)
#pragma unroll
            for (int j = 0; j < 4; ++j) {
                acc[i][j] = __builtin_amdgcn_mfma_f32_16x16x32_bf16(afh[i], bfh[j], acc[i][j], 0, 0, 0);
                acc[i][j] = __builtin_amdgcn_mfma_f32_16x16x32_bf16(afh[i], bfl[j], acc[i][j], 0, 0, 0);
                acc[i][j] = __builtin_amdgcn_mfma_f32_16x16x32_bf16(afl[i], bfh[j], acc[i][j], 0, 0, 0);
            }
        __syncthreads();
    }

#pragma unroll
    for (int i = 0; i < 4; ++i) {
        int rbase = row0 + i * 16 + (lane >> 4) * 4;
#pragma unroll
        for (int j = 0; j < 4; ++j) {
            int col = wn * 64 + j * 16 + (lane & 15);
#pragma unroll
            for (int q = 0; q < 4; ++q) {
                int row = rbase + q;
                if (row < NN) Ch[(size_t)row * 256 + col] = (half_t)acc[i][j][q];
            }
        }
    }
    float alv[4], arv[4];
#pragma unroll
    for (int j = 0; j < 4; ++j) {
        int col = wn * 64 + j * 16 + (lane & 15);
        alv[j] = al[col];
        arv[j] = ar[col];
    }
#pragma unroll
    for (int i = 0; i < 4; ++i)
#pragma unroll
        for (int q = 0; q < 4; ++q) {
            float ep = acc[i][0][q] * alv[0] + acc[i][1][q] * alv[1]
                     + acc[i][2][q] * alv[2] + acc[i][3][q] * alv[3];
            float rp_ = acc[i][0][q] * arv[0] + acc[i][1][q] * arv[1]
                      + acc[i][2][q] * arv[2] + acc[i][3][q] * arv[3];
#pragma unroll
            for (int msk = 1; msk < 16; msk <<= 1) {
                ep += __shfl_xor(ep, msk);
                rp_ += __shfl_xor(rp_, msk);
            }
            if ((lane & 15) == 0) {
                int row = row0 + i * 16 + (lane >> 4) * 4 + q;
                if (row < NN) {
                    el[row * 4 + wn] = ep;
                    er[row * 4 + wn] = rp_;
                }
            }
        }
}

// ---------------- fused layer-0 GEMM + edge scatter ----------------

__global__ __launch_bounds__(256) void gemm0_scatter_kernel(
    const float* __restrict__ x,
    const short* __restrict__ Wthi, const short* __restrict__ Wtlo,
    half_t* __restrict__ featA,
    const float* __restrict__ alA, const float* __restrict__ arA,
    float* __restrict__ elA, float* __restrict__ erA,
    const int* __restrict__ src, const int* __restrict__ dst,
    int* __restrict__ cursor, long long* __restrict__ spair,
    int rowTiles) {
    const int m = blockIdx.y;
    if ((int)blockIdx.x < rowTiles) {
        gemm_core<0>(blockIdx.x, m, x, nullptr, Wthi, Wtlo, featA, alA, arA, elA, erA);
    } else {
        int e = (blockIdx.x - rowTiles) * 256 + threadIdx.x;
        if (e < EE) {
            int d = dst[m * EE + e];
            int pos = atomicAdd(&cursor[m * (NN + 1) + d], 1);
            long long p = ((long long)d << 32) | (unsigned)src[m * EE + e];
            __builtin_nontemporal_store(p, &spair[(size_t)m * EE + pos]);
        }
    }
}

__global__ __launch_bounds__(256) void mfma_gemm1_kernel(
    const half_t* __restrict__ Hb,
    const short* __restrict__ Wthi, const short* __restrict__ Wtlo,
    half_t* __restrict__ featA,
    const float* __restrict__ alA, const float* __restrict__ arA,
    float* __restrict__ elA, float* __restrict__ erA) {
    gemm_core<1>(blockIdx.x, blockIdx.y, nullptr, Hb, Wthi, Wtlo, featA, alA, arA, elA, erA);
}

// ---------------- semantic GEMM: BM=128 x BN=128, fp16 A (unchanged) -------

__global__ __launch_bounds__(256) void sem_gemm(
    const half_t* __restrict__ A16,
    const short* __restrict__ Wthi, const short* __restrict__ Wtlo,
    float* __restrict__ P,
    const float* __restrict__ b1, const float* __restrict__ w2,
    float* __restrict__ wsum,
    int nrows) {
    __shared__ short Ah[128 * 32], Al[128 * 32], Bh[128 * 32], Bl[128 * 32]; // 32 KB
    const int t = threadIdx.x;
    const int lane = t & 63;
    const int wave = t >> 6;
    const int wm = wave >> 1, wn = wave & 1;
    const int row0 = blockIdx.x * 128;
    const short* A1 = (const short*)A16;
    f32x4 acc[4][4] = {};

    const int r0 = (t * 2) >> 2, c0 = (t * 2) & 3;
    const int r1 = (t * 2 + 1) >> 2, c1 = (t * 2 + 1) & 3;
    const int aoff0 = r0 * 32 + ((c0 ^ ((r0 >> 1) & 3)) << 3);
    const int aoff1 = r1 * 32 + ((c1 ^ ((r1 >> 1) & 3)) << 3);
    const int arow0 = row0 + r0, arow1 = row0 + r1;

    s16x8 p0 = {0,0,0,0,0,0,0,0}, p1 = {0,0,0,0,0,0,0,0};
    if (arow0 < nrows) p0 = *(const s16x8*)(A1 + (size_t)arow0 * 256 + c0 * 8);
    if (arow1 < nrows) p1 = *(const s16x8*)(A1 + (size_t)arow1 * 256 + c1 * 8);

    for (int k0 = 0; k0 < 256; k0 += 32) {
        {
            s16x8 hh, ll;
#pragma unroll
            for (int j = 0; j < 8; ++j) {
                float v = h2f(p0[j]);
                short hs = bfhi(v);
                hh[j] = hs; ll[j] = bfhi(v - bf2f(hs));
            }
            *(s16x8*)&Ah[aoff0] = hh; *(s16x8*)&Al[aoff0] = ll;
#pragma unroll
            for (int j = 0; j < 8; ++j) {
                float v = h2f(p1[j]);
                short hs = bfhi(v);
                hh[j] = hs; ll[j] = bfhi(v - bf2f(hs));
            }
            *(s16x8*)&Ah[aoff1] = hh; *(s16x8*)&Al[aoff1] = ll;
        }
#pragma unroll
        for (int u = 0; u < 2; ++u) {
            int idx = t * 2 + u;
            int n = idx >> 2, c = idx & 3;
            s16x8 h = *(const s16x8*)(Wthi + (size_t)n * 256 + k0 + c * 8);
            s16x8 l = *(const s16x8*)(Wtlo + (size_t)n * 256 + k0 + c * 8);
            int off = n * 32 + ((c ^ ((n >> 1) & 3)) << 3);
            *(s16x8*)&Bh[off] = h;
            *(s16x8*)&Bl[off] = l;
        }
        __syncthreads();
        if (k0 + 32 < 256) {
            p0 = s16x8{0,0,0,0,0,0,0,0}; p1 = s16x8{0,0,0,0,0,0,0,0};
            if (arow0 < nrows) p0 = *(const s16x8*)(A1 + (size_t)arow0 * 256 + k0 + 32 + c0 * 8);
            if (arow1 < nrows) p1 = *(const s16x8*)(A1 + (size_t)arow1 * 256 + k0 + 32 + c1 * 8);
        }
        int fr = lane & 15, ac = lane >> 4;
        s16x8 afh[4], afl[4], bfh[4], bfl[4];
#pragma unroll
        for (int i = 0; i < 4; ++i) {
            int rr = wm * 64 + i * 16 + fr;
            int off = rr * 32 + ((ac ^ ((rr >> 1) & 3)) << 3);
            afh[i] = *(const s16x8*)&Ah[off];
            afl[i] = *(const s16x8*)&Al[off];
        }
#pragma unroll
        for (int j = 0; j < 4; ++j) {
            int n = wn * 64 + j * 16 + fr;
            int off = n * 32 + ((ac ^ ((n >> 1) & 3)) << 3);
            bfh[j] = *(const s16x8*)&Bh[off];
            bfl[j] = *(const s16x8*)&Bl[off];
        }
#pragma unroll
        for (int i = 0; i < 4; ++i)
#pragma unroll
            for (int j = 0; j < 4; ++j) {
                acc[i][j] = __builtin_amdgcn_mfma_f32_16x16x32_bf16(afh[i], bfh[j], acc[i][j], 0, 0, 0);
                acc[i][j] = __builtin_amdgcn_mfma_f32_16x16x32_bf16(afh[i], bfl[j], acc[i][j], 0, 0, 0);
                acc[i][j] = __builtin_amdgcn_mfma_f32_16x16x32_bf16(afl[i], bfh[j], acc[i][j], 0, 0, 0);
            }
        __syncthreads();
    }

    float* wp = (float*)&Ah[0];
    if (t < 3) wp[t] = 0.f;
    __syncthreads();
    int fr = lane & 15, ac = lane >> 4;
    if (wn == 0) {
        float b1v[4], w2v[4];
#pragma unroll
        for (int j = 0; j < 4; ++j) {
            int col = j * 16 + fr;
            b1v[j] = b1[col];
            w2v[j] = w2[col];
        }
#pragma unroll
        for (int i = 0; i < 4; ++i)
#pragma unroll
            for (int q = 0; q < 4; ++q) {
                float ep = tanhf(acc[i][0][q] + b1v[0]) * w2v[0]
                         + tanhf(acc[i][1][q] + b1v[1]) * w2v[1]
                         + tanhf(acc[i][2][q] + b1v[2]) * w2v[2]
                         + tanhf(acc[i][3][q] + b1v[3]) * w2v[3];
#pragma unroll
                for (int msk = 1; msk < 16; msk <<= 1) ep += __shfl_xor(ep, msk);
                if (fr == 0) {
                    int row = row0 + wm * 64 + i * 16 + ac * 4 + q;
                    if (row < nrows) atomicAdd(&wp[row / NN], ep);
                }
            }
    } else {
#pragma unroll
        for (int i = 0; i < 4; ++i) {
            int rbase = row0 + wm * 64 + i * 16 + ac * 4;
#pragma unroll
            for (int j = 0; j < 4; ++j) {
                int pcol = j * 16 + fr;
#pragma unroll
                for (int q = 0; q < 4; ++q) {
                    int row = rbase + q;
                    if (row < nrows) P[(size_t)row * 64 + pcol] = acc[i][j][q];
                }
            }
        }
    }
    __syncthreads();
    if (t < 3) atomicAdd(&wsum[t], wp[t]);
}

// ---------------- edge-softmax aggregation (r17-best: unroll-4) ------------

__global__ __launch_bounds__(256) void agg_edges_kernel(const half_t* __restrict__ featA,
                                                        const float* __restrict__ elA,
                                                        const float* __restrict__ erA,
                                                        const int* __restrict__ row_ptrA,
                                                        const long long* __restrict__ spairA,
                                                        const float* __restrict__ biasL,
                                                        half_t* __restrict__ HbA) {
    const int m = blockIdx.y;
    const half_t* feat = featA + (size_t)m * NN * 256;
    const float* el = elA + (size_t)m * NN * 4;
    const float* er = erA + (size_t)m * NN * 4;
    const int* row_ptr = row_ptrA + (size_t)m * (NN + 1);
    const long long* spair = spairA + (size_t)m * EE;
    const float* bias = biasL + m * 256;
    half_t* out = HbA + (size_t)m * NN * 256;

    int wave = threadIdx.x >> 6;
    int lane = threadIdx.x & 63;
    int n = blockIdx.x * 4 + wave;
    int h = lane >> 4;
    int beg = row_ptr[n], end = row_ptr[n + 1];
    float ern = er[n * 4 + h];
    const h16x4* fb = (const h16x4*)feat + lane;
    float a0A = 0.f, a1A = 0.f, a2A = 0.f, a3A = 0.f, dA = 0.f;
    float a0B = 0.f, a1B = 0.f, a2B = 0.f, a3B = 0.f, dB = 0.f;
    float a0C = 0.f, a1C = 0.f, a2C = 0.f, a3C = 0.f, dC = 0.f;
    float a0D = 0.f, a1D = 0.f, a2D = 0.f, a3D = 0.f, dD = 0.f;
    int j = beg;
    for (; j + 3 < end; j += 4) {
        int sA = (int)(unsigned)spair[j];
        int sB = (int)(unsigned)spair[j + 1];
        int sC = (int)(unsigned)spair[j + 2];
        int sD = (int)(unsigned)spair[j + 3];
        float eA = el[sA * 4 + h] + ern; eA = eA > 0.f ? eA : 0.2f * eA; float wA = __expf(eA);
        float eB = el[sB * 4 + h] + ern; eB = eB > 0.f ? eB : 0.2f * eB; float wB = __expf(eB);
        float eC = el[sC * 4 + h] + ern; eC = eC > 0.f ? eC : 0.2f * eC; float wC = __expf(eC);
        float eD = el[sD * 4 + h] + ern; eD = eD > 0.f ? eD : 0.2f * eD; float wD = __expf(eD);
        h16x4 fA = fb[(size_t)sA * 64];
        h16x4 fB = fb[(size_t)sB * 64];
        h16x4 fC = fb[(size_t)sC * 64];
        h16x4 fD = fb[(size_t)sD * 64];
        a0A = fmaf(wA, (float)fA.x, a0A); a1A = fmaf(wA, (float)fA.y, a1A);
        a2A = fmaf(wA, (float)fA.z, a2A); a3A = fmaf(wA, (float)fA.w, a3A); dA += wA;
        a0B = fmaf(wB, (float)fB.x, a0B); a1B = fmaf(wB, (float)fB.y, a1B);
        a2B = fmaf(wB, (float)fB.z, a2B); a3B = fmaf(wB, (float)fB.w, a3B); dB += wB;
        a0C = fmaf(wC, (float)fC.x, a0C); a1C = fmaf(wC, (float)fC.y, a1C);
        a2C = fmaf(wC, (float)fC.z, a2C); a3C = fmaf(wC, (float)fC.w, a3C); dC += wC;
        a0D = fmaf(wD, (float)fD.x, a0D); a1D = fmaf(wD, (float)fD.y, a1D);
        a2D = fmaf(wD, (float)fD.z, a2D); a3D = fmaf(wD, (float)fD.w, a3D); dD += wD;
    }
    for (; j < end; ++j) {
        int s = (int)(unsigned)spair[j];
        float e = el[s * 4 + h] + ern;
        e = e > 0.f ? e : 0.2f * e;
        float w = __expf(e);
        h16x4 f = fb[(size_t)s * 64];
        a0A = fmaf(w, (float)f.x, a0A); a1A = fmaf(w, (float)f.y, a1A);
        a2A = fmaf(w, (float)f.z, a2A); a3A = fmaf(w, (float)f.w, a3A); dA += w;
    }
    float den = fmaxf((dA + dB) + (dC + dD), 1e-9f);
    int col = lane * 4;
    float o0 = ((a0A + a0B) + (a0C + a0D)) / den + bias[col + 0];
    float o1 = ((a1A + a1B) + (a1C + a1D)) / den + bias[col + 1];
    float o2 = ((a2A + a2B) + (a2C + a2D)) / den + bias[col + 2];
    float o3 = ((a3A + a3B) + (a3C + a3D)) / den + bias[col + 3];
    o0 = o0 > 0.f ? o0 : __expf(o0) - 1.0f;
    o1 = o1 > 0.f ? o1 : __expf(o1) - 1.0f;
    o2 = o2 > 0.f ? o2 : __expf(o2) - 1.0f;
    o3 = o3 > 0.f ? o3 : __expf(o3) - 1.0f;
    h16x4 ov; ov.x = (half_t)o0; ov.y = (half_t)o1; ov.z = (half_t)o2; ov.w = (half_t)o3;
    ((h16x4*)(out + (size_t)n * 256))[lane] = ov;
}

// ---------------- final combine (beta inlined from wsum) ----------------

__global__ __launch_bounds__(256) void combine_out_kernel(const float* __restrict__ P,
                                                          const float* __restrict__ wsum,
                                                          const float* __restrict__ bp,
                                                          float* __restrict__ out) {
    int idx4 = blockIdx.x * 256 + threadIdx.x;
    if (idx4 >= NN * 64 / 4) return;
    float w0 = wsum[0] / (float)NN, w1 = wsum[1] / (float)NN, w2 = wsum[2] / (float)NN;
    float mx = fmaxf(w0, fmaxf(w1, w2));
    float e0 = __expf(w0 - mx), e1 = __expf(w1 - mx), e2 = __expf(w2 - mx);
    float inv = 1.f / (e0 + e1 + e2);
    float b0 = e0 * inv, b1 = e1 * inv, b2 = e2 * inv;
    float4 p0 = ((const float4*)P)[idx4];
    float4 p1 = ((const float4*)P)[idx4 + NN * 16];
    float4 p2 = ((const float4*)P)[idx4 + NN * 32];
    float4 bpv = *(const float4*)(bp + ((idx4 * 4) & 63));
    float4 o;
    o.x = b0 * p0.x + b1 * p1.x + b2 * p2.x + bpv.x;
    o.y = b0 * p0.y + b1 * p1.y + b2 * p2.y + bpv.y;
    o.z = b0 * p0.z + b1 * p1.z + b2 * p2.z + bpv.z;
    o.w = b0 * p0.w + b1 * p1.w + b2 * p2.w + bpv.w;
    ((float4*)out)[idx4] = o;
}

// ---------------- host launch ----------------

extern "C" void kernel_launch(void* const* d_in, const int* in_sizes, int n_in,
                              void* d_out, int out_size, void* d_ws, size_t ws_size,
                              hipStream_t stream) {
    const float* x        = (const float*)d_in[0];
    const float* W_gat    = (const float*)d_in[1];
    const float* attn_l   = (const float*)d_in[2];
    const float* attn_r   = (const float*)d_in[3];
    const float* bias_gat = (const float*)d_in[4];
    const float* W1       = (const float*)d_in[5];
    const float* b1       = (const float*)d_in[6];
    const float* W2       = (const float*)d_in[7];
    const float* Wp       = (const float*)d_in[8];
    const float* bp       = (const float*)d_in[9];
    const int*   src      = (const int*)d_in[10];
    const int*   dst      = (const int*)d_in[11];
    float* out = (float*)d_out;

    char* ws = (char*)d_ws;
    size_t off = 0;
    auto alloc = [&](size_t bytes) { size_t o = off; off = (off + bytes + 255) & ~(size_t)255; return o; };
    half_t* Hb      = (half_t*)(ws + alloc((size_t)MM * NN * 256 * 2));
    half_t* feat    = (half_t*)(ws + alloc((size_t)MM * NN * 256 * 2));
    float*  P       = (float*)(ws + alloc((size_t)MM * NN * 64 * 4));
    float*  el      = (float*)(ws + alloc((size_t)MM * NN * 4 * 4));
    float*  er      = (float*)(ws + alloc((size_t)MM * NN * 4 * 4));
    int*    counts  = (int*)(ws + alloc((size_t)MM * NN * 4));
    int*    row_ptr = (int*)(ws + alloc((size_t)MM * (NN + 1) * 4));
    int*    cursor  = (int*)(ws + alloc((size_t)MM * (NN + 1) * 4));
    long long* spair = (long long*)(ws + alloc((size_t)MM * EE * 8));
    int*    bsum    = (int*)(ws + alloc((size_t)MM * NCHUNK * 4));
    short*  Whi     = (short*)(ws + alloc((size_t)W_TOT * 2));
    short*  Wlo     = (short*)(ws + alloc((size_t)W_TOT * 2));
    float*  wsum    = (float*)(ws + alloc(16));

    const int histBlocks = (EE + 255) / 256;       // 1563

    init_kernel<<<dim3((MM * NN + 255) / 256), 256, 0, stream>>>(counts, wsum);
    hist_splitW_kernel<<<dim3(histBlocks + SPLITW_PER_Y, MM), 256, 0, stream>>>(
        dst, counts, W_gat, W1, Wp, Whi, Wlo, histBlocks);
    scan_partial_kernel<<<dim3(NCHUNK, MM), 256, 0, stream>>>(counts, row_ptr, bsum);
    scan_top_kernel<<<dim3(1), 256, 0, stream>>>(bsum);
    scan_add_kernel<<<dim3(NCHUNK, MM), 256, 0, stream>>>(bsum, row_ptr, cursor);

    const int rowTiles = (NN + 63) / 64;           // 782

    // layer 0: fused GEMM<0> + scatter (independent work, co-dispatched)
    gemm0_scatter_kernel<<<dim3(rowTiles + histBlocks, MM), 256, 0, stream>>>(
        x, Whi, Wlo, feat, attn_l, attn_r, el, er,
        src, dst, cursor, spair, rowTiles);
    agg_edges_kernel<<<dim3(NN / 4, MM), 256, 0, stream>>>(
        feat, el, er, row_ptr, spair, bias_gat, Hb);

    // layer 1
    mfma_gemm1_kernel<<<dim3(rowTiles, MM), 256, 0, stream>>>(
        Hb, Whi + (size_t)MM * 65536, Wlo + (size_t)MM * 65536,
        feat, attn_l + (size_t)MM * 256, attn_r + (size_t)MM * 256, el, er);
    agg_edges_kernel<<<dim3(NN / 4, MM), 256, 0, stream>>>(
        feat, el, er, row_ptr, spair, bias_gat + (size_t)MM * 256, Hb);

    // merged semantic + projection pass over all 3 metapaths (Hb contiguous)
    sem_gemm<<<dim3((MM * NN + 127) / 128), 256, 0, stream>>>(
        Hb, Whi + WG_ELEMS, Wlo + WG_ELEMS, P, b1, W2, wsum, MM * NN);
    combine_out_kernel<<<dim3((NN * 16 + 255) / 256), 256, 0, stream>>>(P, wsum, bp, out);
}

// Round 20
// 568.079 us; speedup vs baseline: 1.1044x; 1.0092x over previous
//
#include <hip/hip_runtime.h>

#define NN 50000
#define EE 400000
#define MM 3
#define CHUNK 2048
#define NCHUNK ((NN + CHUNK - 1) / CHUNK)   // 25

typedef float f32x4 __attribute__((ext_vector_type(4)));
typedef short s16x8 __attribute__((ext_vector_type(8)));
typedef _Float16 half_t;
typedef _Float16 h16x4 __attribute__((ext_vector_type(4)));
typedef _Float16 h16x8 __attribute__((ext_vector_type(8)));

union FU { float f; unsigned u; };

__device__ inline float h2f(short bits) {
    union HU { short s; _Float16 h; } u; u.s = bits; return (float)u.h;
}
__device__ inline short f16hi(float x) {
    union HU { _Float16 h; short s; } u; u.h = (_Float16)x; return u.s;
}

// ---------------- CSR build ----------------

__global__ __launch_bounds__(256) void init_kernel(int* counts, float* wsum) {
    int idx = blockIdx.x * 256 + threadIdx.x;
    if (idx < MM * NN) counts[idx] = 0;
    if (idx < MM) wsum[idx] = 0.0f;
}

#define WG_ELEMS (6 * 256 * 256)
#define W_TOT (WG_ELEMS + 128 * 256)
#define SPLITW_BLOCKS ((W_TOT + 255) / 256)             // 1664
#define SPLITW_PER_Y ((SPLITW_BLOCKS + MM - 1) / MM)    // 555

// hist (per-metapath) co-dispatched with splitW (independent work).
// Weights split as f16 hi + f16 lo (22-bit combined mantissa).
__global__ __launch_bounds__(256) void hist_splitW_kernel(
    const int* __restrict__ dst, int* __restrict__ counts,
    const float* __restrict__ Wg, const float* __restrict__ W1,
    const float* __restrict__ Wp,
    short* __restrict__ Whi, short* __restrict__ Wlo, int histBlocks) {
    const int m = blockIdx.y;
    if ((int)blockIdx.x < histBlocks) {
        int e = blockIdx.x * 256 + threadIdx.x;
        if (e < EE) atomicAdd(&counts[m * NN + dst[m * EE + e]], 1);
    } else {
        int b = ((int)blockIdx.x - histBlocks) * MM + m;
        int idx = b * 256 + threadIdx.x;
        if (idx >= W_TOT) return;
        float v;
        if (idx < WG_ELEMS) {
            int mat = idx >> 16, rem = idx & 65535;
            int n = rem >> 8, k = rem & 255;
            v = Wg[mat * 65536 + k * 256 + n];
        } else {
            int i2 = idx - WG_ELEMS;
            int n = i2 >> 8, k = i2 & 255;
            v = (n < 64) ? W1[k * 64 + n] : Wp[k * 64 + n - 64];
        }
        short h = f16hi(v);
        Whi[idx] = h;
        Wlo[idx] = f16hi(v - h2f(h));
    }
}

__global__ __launch_bounds__(256) void scan_partial_kernel(const int* __restrict__ counts,
                                                           int* __restrict__ rp,
                                                           int* __restrict__ bsum) {
    int m = blockIdx.y, ch = blockIdx.x;
    const int* c = counts + m * NN;
    int* r = rp + m * (NN + 1);
    int t = threadIdx.x, lane = t & 63, wave = t >> 6;
    int i0 = ch * CHUNK + t * 8;
    int v[8]; int s = 0;
#pragma unroll
    for (int k = 0; k < 8; ++k) { int i = i0 + k; v[k] = (i < NN) ? c[i] : 0; s += v[k]; }
    int incl = s;
#pragma unroll
    for (int off = 1; off < 64; off <<= 1) {
        int u = __shfl_up(incl, off);
        if (lane >= off) incl += u;
    }
    int excl = incl - s;
    __shared__ int wsh[4];
    if (lane == 63) wsh[wave] = incl;
    __syncthreads();
    int woff = 0;
    for (int w = 0; w < wave; ++w) woff += wsh[w];
    int run = excl + woff;
#pragma unroll
    for (int k = 0; k < 8; ++k) { int i = i0 + k; if (i < NN) r[i] = run; run += v[k]; }
    if (t == 255) bsum[m * NCHUNK + ch] = woff + incl;
}

__global__ __launch_bounds__(256) void scan_top_kernel(int* __restrict__ bsum) {
    int wave = threadIdx.x >> 6, lane = threadIdx.x & 63;
    if (wave < MM) {
        int v = (lane < NCHUNK) ? bsum[wave * NCHUNK + lane] : 0;
        int incl = v;
#pragma unroll
        for (int off = 1; off < 64; off <<= 1) {
            int u = __shfl_up(incl, off);
            if (lane >= off) incl += u;
        }
        if (lane < NCHUNK) bsum[wave * NCHUNK + lane] = incl - v;
    }
}

__global__ __launch_bounds__(256) void scan_add_kernel(const int* __restrict__ bsum,
                                                       int* __restrict__ rp,
                                                       int* __restrict__ cur) {
    int m = blockIdx.y, ch = blockIdx.x;
    int off = bsum[m * NCHUNK + ch];
    int* r = rp + m * (NN + 1);
    int* q = cur + m * (NN + 1);
    int i0 = ch * CHUNK + threadIdx.x * 8;
#pragma unroll
    for (int k = 0; k < 8; ++k) {
        int i = i0 + k;
        if (i < NN) { int val = r[i] + off; r[i] = val; q[i] = val; }
    }
    if (ch == 0 && threadIdx.x == 0) r[NN] = EE;
}

// ---------------- GEMM core: BM=64 x BN=256, 256 thr, f16 2-product -------
// A = single f16 operand (layer-1: exact fp16 Hb, zero-convert staging;
// layer-0: f16(x)). B = f16 hi + f16 lo -> 2 MFMAs per frag pair (was 3
// bf16 products + 16-op A-split). LDS 36 KB.

template<int AMODE>
__device__ __forceinline__ void gemm_core(
    int bx, int m,
    const float* __restrict__ Af, const half_t* __restrict__ A16,
    const short* __restrict__ Wthi, const short* __restrict__ Wtlo,
    half_t* __restrict__ featA,
    const float* __restrict__ alA, const float* __restrict__ arA,
    float* __restrict__ elA, float* __restrict__ erA) {
    __shared__ short Ah[64 * 32], Bh[256 * 32], Bl[256 * 32];  // 36864 B
    const int t = threadIdx.x;
    const int lane = t & 63;
    const int wn = t >> 6;
    const int row0 = bx * 64;
    const float*  A0 = Af + (size_t)m * NN * 256;
    const short*  A1 = (const short*)(A16 + (size_t)m * NN * 256);
    const short*  Bgh = Wthi + (size_t)m * 65536;
    const short*  Bgl = Wtlo + (size_t)m * 65536;
    half_t* Ch = featA + (size_t)m * NN * 256;
    const float* al = alA + m * 256;
    const float* ar = arA + m * 256;
    float* el = elA + (size_t)m * NN * 4;
    float* er = erA + (size_t)m * NN * 4;
    f32x4 acc[4][4] = {};

    const int r = t >> 2, c0 = t & 3;
    const int aoff = r * 32 + ((c0 ^ ((r >> 1) & 3)) << 3);
    const int arow = row0 + r;
    const bool aval = (arow < NN);

    s16x8 praw = {0,0,0,0,0,0,0,0};
    float4 pf0 = make_float4(0.f,0.f,0.f,0.f), pf1 = make_float4(0.f,0.f,0.f,0.f);

    if (AMODE == 1) {
        if (aval) praw = *(const s16x8*)(A1 + (size_t)arow * 256 + c0 * 8);
    } else {
        if (aval) {
            pf0 = *(const float4*)(A0 + (size_t)arow * 256 + c0 * 8);
            pf1 = *(const float4*)(A0 + (size_t)arow * 256 + c0 * 8 + 4);
        }
    }

    for (int k0 = 0; k0 < 256; k0 += 32) {
        // ---- stage A: fp16 direct (AMODE 1) or f16-convert (AMODE 0) ----
        if (AMODE == 1) {
            *(s16x8*)&Ah[aoff] = praw;
        } else {
            float v[8] = {pf0.x, pf0.y, pf0.z, pf0.w, pf1.x, pf1.y, pf1.z, pf1.w};
            s16x8 hh;
#pragma unroll
            for (int j = 0; j < 8; ++j) hh[j] = f16hi(v[j]);
            *(s16x8*)&Ah[aoff] = hh;
        }
        // ---- stage B (256 cols x 32 k), 4 units/thread ----
#pragma unroll
        for (int u = 0; u < 4; ++u) {
            int n = u * 64 + (t >> 2), c = t & 3;
            s16x8 h = *(const s16x8*)(Bgh + (size_t)n * 256 + k0 + c * 8);
            s16x8 l = *(const s16x8*)(Bgl + (size_t)n * 256 + k0 + c * 8);
            int off = n * 32 + ((c ^ ((n >> 1) & 3)) << 3);
            *(s16x8*)&Bh[off] = h;
            *(s16x8*)&Bl[off] = l;
        }
        __syncthreads();
        // ---- prefetch A for k0+32 (wait lands at next iter's ds_write) ----
        if (k0 + 32 < 256) {
            if (AMODE == 1) {
                praw = s16x8{0,0,0,0,0,0,0,0};
                if (aval) praw = *(const s16x8*)(A1 + (size_t)arow * 256 + k0 + 32 + c0 * 8);
            } else {
                pf0 = make_float4(0.f,0.f,0.f,0.f); pf1 = make_float4(0.f,0.f,0.f,0.f);
                if (aval) {
                    pf0 = *(const float4*)(A0 + (size_t)arow * 256 + k0 + 32 + c0 * 8);
                    pf1 = *(const float4*)(A0 + (size_t)arow * 256 + k0 + 32 + c0 * 8 + 4);
                }
            }
        }
        // ---- MFMA: 16 frag pairs x 2 products ----
        int fr = lane & 15, ac = lane >> 4;
        h16x8 af[4], bfh[4], bfl[4];
#pragma unroll
        for (int i = 0; i < 4; ++i) {
            int rr = i * 16 + fr;
            int off = rr * 32 + ((ac ^ ((rr >> 1) & 3)) << 3);
            af[i] = *(const h16x8*)&Ah[off];
        }
#pragma unroll
        for (int j = 0; j < 4; ++j) {
            int n = wn * 64 + j * 16 + fr;
            int off = n * 32 + ((ac ^ ((n >> 1) & 3)) << 3);
            bfh[j] = *(const h16x8*)&Bh[off];
            bfl[j] = *(const h16x8*)&Bl[off];
        }
#pragma unroll
        for (int i = 0; i < 4; ++i)
#pragma unroll
            for (int j = 0; j < 4; ++j) {
                acc[i][j] = __builtin_amdgcn_mfma_f32_16x16x32_f16(af[i], bfh[j], acc[i][j], 0, 0, 0);
                acc[i][j] = __builtin_amdgcn_mfma_f32_16x16x32_f16(af[i], bfl[j], acc[i][j], 0, 0, 0);
            }
        __syncthreads();
    }

#pragma unroll
    for (int i = 0; i < 4; ++i) {
        int rbase = row0 + i * 16 + (lane >> 4) * 4;
#pragma unroll
        for (int j = 0; j < 4; ++j) {
            int col = wn * 64 + j * 16 + (lane & 15);
#pragma unroll
            for (int q = 0; q < 4; ++q) {
                int row = rbase + q;
                if (row < NN) Ch[(size_t)row * 256 + col] = (half_t)acc[i][j][q];
            }
        }
    }
    float alv[4], arv[4];
#pragma unroll
    for (int j = 0; j < 4; ++j) {
        int col = wn * 64 + j * 16 + (lane & 15);
        alv[j] = al[col];
        arv[j] = ar[col];
    }
#pragma unroll
    for (int i = 0; i < 4; ++i)
#pragma unroll
        for (int q = 0; q < 4; ++q) {
            float ep = acc[i][0][q] * alv[0] + acc[i][1][q] * alv[1]
                     + acc[i][2][q] * alv[2] + acc[i][3][q] * alv[3];
            float rp_ = acc[i][0][q] * arv[0] + acc[i][1][q] * arv[1]
                      + acc[i][2][q] * arv[2] + acc[i][3][q] * arv[3];
#pragma unroll
            for (int msk = 1; msk < 16; msk <<= 1) {
                ep += __shfl_xor(ep, msk);
                rp_ += __shfl_xor(rp_, msk);
            }
            if ((lane & 15) == 0) {
                int row = row0 + i * 16 + (lane >> 4) * 4 + q;
                if (row < NN) {
                    el[row * 4 + wn] = ep;
                    er[row * 4 + wn] = rp_;
                }
            }
        }
}

// ---------------- fused layer-0 GEMM + edge scatter ----------------

__global__ __launch_bounds__(256) void gemm0_scatter_kernel(
    const float* __restrict__ x,
    const short* __restrict__ Wthi, const short* __restrict__ Wtlo,
    half_t* __restrict__ featA,
    const float* __restrict__ alA, const float* __restrict__ arA,
    float* __restrict__ elA, float* __restrict__ erA,
    const int* __restrict__ src, const int* __restrict__ dst,
    int* __restrict__ cursor, long long* __restrict__ spair,
    int rowTiles) {
    const int m = blockIdx.y;
    if ((int)blockIdx.x < rowTiles) {
        gemm_core<0>(blockIdx.x, m, x, nullptr, Wthi, Wtlo, featA, alA, arA, elA, erA);
    } else {
        int e = (blockIdx.x - rowTiles) * 256 + threadIdx.x;
        if (e < EE) {
            int d = dst[m * EE + e];
            int pos = atomicAdd(&cursor[m * (NN + 1) + d], 1);
            long long p = ((long long)d << 32) | (unsigned)src[m * EE + e];
            __builtin_nontemporal_store(p, &spair[(size_t)m * EE + pos]);
        }
    }
}

__global__ __launch_bounds__(256) void mfma_gemm1_kernel(
    const half_t* __restrict__ Hb,
    const short* __restrict__ Wthi, const short* __restrict__ Wtlo,
    half_t* __restrict__ featA,
    const float* __restrict__ alA, const float* __restrict__ arA,
    float* __restrict__ elA, float* __restrict__ erA) {
    gemm_core<1>(blockIdx.x, blockIdx.y, nullptr, Hb, Wthi, Wtlo, featA, alA, arA, elA, erA);
}

// ---------------- semantic GEMM: BM=128 x BN=128, f16 2-product ------------

__global__ __launch_bounds__(256) void sem_gemm(
    const half_t* __restrict__ A16,
    const short* __restrict__ Wthi, const short* __restrict__ Wtlo,
    float* __restrict__ P,
    const float* __restrict__ b1, const float* __restrict__ w2,
    float* __restrict__ wsum,
    int nrows) {
    __shared__ short Ah[128 * 32], Bh[128 * 32], Bl[128 * 32]; // 24 KB
    const int t = threadIdx.x;
    const int lane = t & 63;
    const int wave = t >> 6;
    const int wm = wave >> 1, wn = wave & 1;
    const int row0 = blockIdx.x * 128;
    const short* A1 = (const short*)A16;
    f32x4 acc[4][4] = {};

    const int r0 = (t * 2) >> 2, c0 = (t * 2) & 3;
    const int r1 = (t * 2 + 1) >> 2, c1 = (t * 2 + 1) & 3;
    const int aoff0 = r0 * 32 + ((c0 ^ ((r0 >> 1) & 3)) << 3);
    const int aoff1 = r1 * 32 + ((c1 ^ ((r1 >> 1) & 3)) << 3);
    const int arow0 = row0 + r0, arow1 = row0 + r1;

    s16x8 p0 = {0,0,0,0,0,0,0,0}, p1 = {0,0,0,0,0,0,0,0};
    if (arow0 < nrows) p0 = *(const s16x8*)(A1 + (size_t)arow0 * 256 + c0 * 8);
    if (arow1 < nrows) p1 = *(const s16x8*)(A1 + (size_t)arow1 * 256 + c1 * 8);

    for (int k0 = 0; k0 < 256; k0 += 32) {
        *(s16x8*)&Ah[aoff0] = p0;
        *(s16x8*)&Ah[aoff1] = p1;
#pragma unroll
        for (int u = 0; u < 2; ++u) {
            int idx = t * 2 + u;
            int n = idx >> 2, c = idx & 3;
            s16x8 h = *(const s16x8*)(Wthi + (size_t)n * 256 + k0 + c * 8);
            s16x8 l = *(const s16x8*)(Wtlo + (size_t)n * 256 + k0 + c * 8);
            int off = n * 32 + ((c ^ ((n >> 1) & 3)) << 3);
            *(s16x8*)&Bh[off] = h;
            *(s16x8*)&Bl[off] = l;
        }
        __syncthreads();
        if (k0 + 32 < 256) {
            p0 = s16x8{0,0,0,0,0,0,0,0}; p1 = s16x8{0,0,0,0,0,0,0,0};
            if (arow0 < nrows) p0 = *(const s16x8*)(A1 + (size_t)arow0 * 256 + k0 + 32 + c0 * 8);
            if (arow1 < nrows) p1 = *(const s16x8*)(A1 + (size_t)arow1 * 256 + k0 + 32 + c1 * 8);
        }
        int fr = lane & 15, ac = lane >> 4;
        h16x8 af[4], bfh[4], bfl[4];
#pragma unroll
        for (int i = 0; i < 4; ++i) {
            int rr = wm * 64 + i * 16 + fr;
            int off = rr * 32 + ((ac ^ ((rr >> 1) & 3)) << 3);
            af[i] = *(const h16x8*)&Ah[off];
        }
#pragma unroll
        for (int j = 0; j < 4; ++j) {
            int n = wn * 64 + j * 16 + fr;
            int off = n * 32 + ((ac ^ ((n >> 1) & 3)) << 3);
            bfh[j] = *(const h16x8*)&Bh[off];
            bfl[j] = *(const h16x8*)&Bl[off];
        }
#pragma unroll
        for (int i = 0; i < 4; ++i)
#pragma unroll
            for (int j = 0; j < 4; ++j) {
                acc[i][j] = __builtin_amdgcn_mfma_f32_16x16x32_f16(af[i], bfh[j], acc[i][j], 0, 0, 0);
                acc[i][j] = __builtin_amdgcn_mfma_f32_16x16x32_f16(af[i], bfl[j], acc[i][j], 0, 0, 0);
            }
        __syncthreads();
    }

    float* wp = (float*)&Ah[0];
    if (t < 3) wp[t] = 0.f;
    __syncthreads();
    int fr = lane & 15, ac = lane >> 4;
    if (wn == 0) {
        float b1v[4], w2v[4];
#pragma unroll
        for (int j = 0; j < 4; ++j) {
            int col = j * 16 + fr;
            b1v[j] = b1[col];
            w2v[j] = w2[col];
        }
#pragma unroll
        for (int i = 0; i < 4; ++i)
#pragma unroll
            for (int q = 0; q < 4; ++q) {
                float ep = tanhf(acc[i][0][q] + b1v[0]) * w2v[0]
                         + tanhf(acc[i][1][q] + b1v[1]) * w2v[1]
                         + tanhf(acc[i][2][q] + b1v[2]) * w2v[2]
                         + tanhf(acc[i][3][q] + b1v[3]) * w2v[3];
#pragma unroll
                for (int msk = 1; msk < 16; msk <<= 1) ep += __shfl_xor(ep, msk);
                if (fr == 0) {
                    int row = row0 + wm * 64 + i * 16 + ac * 4 + q;
                    if (row < nrows) atomicAdd(&wp[row / NN], ep);
                }
            }
    } else {
#pragma unroll
        for (int i = 0; i < 4; ++i) {
            int rbase = row0 + wm * 64 + i * 16 + ac * 4;
#pragma unroll
            for (int j = 0; j < 4; ++j) {
                int pcol = j * 16 + fr;
#pragma unroll
                for (int q = 0; q < 4; ++q) {
                    int row = rbase + q;
                    if (row < nrows) P[(size_t)row * 64 + pcol] = acc[i][j][q];
                }
            }
        }
    }
    __syncthreads();
    if (t < 3) atomicAdd(&wsum[t], wp[t]);
}

// ---------------- edge-softmax aggregation (r17-best: unroll-4) ------------

__global__ __launch_bounds__(256) void agg_edges_kernel(const half_t* __restrict__ featA,
                                                        const float* __restrict__ elA,
                                                        const float* __restrict__ erA,
                                                        const int* __restrict__ row_ptrA,
                                                        const long long* __restrict__ spairA,
                                                        const float* __restrict__ biasL,
                                                        half_t* __restrict__ HbA) {
    const int m = blockIdx.y;
    const half_t* feat = featA + (size_t)m * NN * 256;
    const float* el = elA + (size_t)m * NN * 4;
    const float* er = erA + (size_t)m * NN * 4;
    const int* row_ptr = row_ptrA + (size_t)m * (NN + 1);
    const long long* spair = spairA + (size_t)m * EE;
    const float* bias = biasL + m * 256;
    half_t* out = HbA + (size_t)m * NN * 256;

    int wave = threadIdx.x >> 6;
    int lane = threadIdx.x & 63;
    int n = blockIdx.x * 4 + wave;
    int h = lane >> 4;
    int beg = row_ptr[n], end = row_ptr[n + 1];
    float ern = er[n * 4 + h];
    const h16x4* fb = (const h16x4*)feat + lane;
    float a0A = 0.f, a1A = 0.f, a2A = 0.f, a3A = 0.f, dA = 0.f;
    float a0B = 0.f, a1B = 0.f, a2B = 0.f, a3B = 0.f, dB = 0.f;
    float a0C = 0.f, a1C = 0.f, a2C = 0.f, a3C = 0.f, dC = 0.f;
    float a0D = 0.f, a1D = 0.f, a2D = 0.f, a3D = 0.f, dD = 0.f;
    int j = beg;
    for (; j + 3 < end; j += 4) {
        int sA = (int)(unsigned)spair[j];
        int sB = (int)(unsigned)spair[j + 1];
        int sC = (int)(unsigned)spair[j + 2];
        int sD = (int)(unsigned)spair[j + 3];
        float eA = el[sA * 4 + h] + ern; eA = eA > 0.f ? eA : 0.2f * eA; float wA = __expf(eA);
        float eB = el[sB * 4 + h] + ern; eB = eB > 0.f ? eB : 0.2f * eB; float wB = __expf(eB);
        float eC = el[sC * 4 + h] + ern; eC = eC > 0.f ? eC : 0.2f * eC; float wC = __expf(eC);
        float eD = el[sD * 4 + h] + ern; eD = eD > 0.f ? eD : 0.2f * eD; float wD = __expf(eD);
        h16x4 fA = fb[(size_t)sA * 64];
        h16x4 fB = fb[(size_t)sB * 64];
        h16x4 fC = fb[(size_t)sC * 64];
        h16x4 fD = fb[(size_t)sD * 64];
        a0A = fmaf(wA, (float)fA.x, a0A); a1A = fmaf(wA, (float)fA.y, a1A);
        a2A = fmaf(wA, (float)fA.z, a2A); a3A = fmaf(wA, (float)fA.w, a3A); dA += wA;
        a0B = fmaf(wB, (float)fB.x, a0B); a1B = fmaf(wB, (float)fB.y, a1B);
        a2B = fmaf(wB, (float)fB.z, a2B); a3B = fmaf(wB, (float)fB.w, a3B); dB += wB;
        a0C = fmaf(wC, (float)fC.x, a0C); a1C = fmaf(wC, (float)fC.y, a1C);
        a2C = fmaf(wC, (float)fC.z, a2C); a3C = fmaf(wC, (float)fC.w, a3C); dC += wC;
        a0D = fmaf(wD, (float)fD.x, a0D); a1D = fmaf(wD, (float)fD.y, a1D);
        a2D = fmaf(wD, (float)fD.z, a2D); a3D = fmaf(wD, (float)fD.w, a3D); dD += wD;
    }
    for (; j < end; ++j) {
        int s = (int)(unsigned)spair[j];
        float e = el[s * 4 + h] + ern;
        e = e > 0.f ? e : 0.2f * e;
        float w = __expf(e);
        h16x4 f = fb[(size_t)s * 64];
        a0A = fmaf(w, (float)f.x, a0A); a1A = fmaf(w, (float)f.y, a1A);
        a2A = fmaf(w, (float)f.z, a2A); a3A = fmaf(w, (float)f.w, a3A); dA += w;
    }
    float den = fmaxf((dA + dB) + (dC + dD), 1e-9f);
    int col = lane * 4;
    float o0 = ((a0A + a0B) + (a0C + a0D)) / den + bias[col + 0];
    float o1 = ((a1A + a1B) + (a1C + a1D)) / den + bias[col + 1];
    float o2 = ((a2A + a2B) + (a2C + a2D)) / den + bias[col + 2];
    float o3 = ((a3A + a3B) + (a3C + a3D)) / den + bias[col + 3];
    o0 = o0 > 0.f ? o0 : __expf(o0) - 1.0f;
    o1 = o1 > 0.f ? o1 : __expf(o1) - 1.0f;
    o2 = o2 > 0.f ? o2 : __expf(o2) - 1.0f;
    o3 = o3 > 0.f ? o3 : __expf(o3) - 1.0f;
    h16x4 ov; ov.x = (half_t)o0; ov.y = (half_t)o1; ov.z = (half_t)o2; ov.w = (half_t)o3;
    ((h16x4*)(out + (size_t)n * 256))[lane] = ov;
}

// ---------------- final combine (beta inlined from wsum) ----------------

__global__ __launch_bounds__(256) void combine_out_kernel(const float* __restrict__ P,
                                                          const float* __restrict__ wsum,
                                                          const float* __restrict__ bp,
                                                          float* __restrict__ out) {
    int idx4 = blockIdx.x * 256 + threadIdx.x;
    if (idx4 >= NN * 64 / 4) return;
    float w0 = wsum[0] / (float)NN, w1 = wsum[1] / (float)NN, w2 = wsum[2] / (float)NN;
    float mx = fmaxf(w0, fmaxf(w1, w2));
    float e0 = __expf(w0 - mx), e1 = __expf(w1 - mx), e2 = __expf(w2 - mx);
    float inv = 1.f / (e0 + e1 + e2);
    float b0 = e0 * inv, b1 = e1 * inv, b2 = e2 * inv;
    float4 p0 = ((const float4*)P)[idx4];
    float4 p1 = ((const float4*)P)[idx4 + NN * 16];
    float4 p2 = ((const float4*)P)[idx4 + NN * 32];
    float4 bpv = *(const float4*)(bp + ((idx4 * 4) & 63));
    float4 o;
    o.x = b0 * p0.x + b1 * p1.x + b2 * p2.x + bpv.x;
    o.y = b0 * p0.y + b1 * p1.y + b2 * p2.y + bpv.y;
    o.z = b0 * p0.z + b1 * p1.z + b2 * p2.z + bpv.z;
    o.w = b0 * p0.w + b1 * p1.w + b2 * p2.w + bpv.w;
    ((float4*)out)[idx4] = o;
}

// ---------------- host launch ----------------

extern "C" void kernel_launch(void* const* d_in, const int* in_sizes, int n_in,
                              void* d_out, int out_size, void* d_ws, size_t ws_size,
                              hipStream_t stream) {
    const float* x        = (const float*)d_in[0];
    const float* W_gat    = (const float*)d_in[1];
    const float* attn_l   = (const float*)d_in[2];
    const float* attn_r   = (const float*)d_in[3];
    const float* bias_gat = (const float*)d_in[4];
    const float* W1       = (const float*)d_in[5];
    const float* b1       = (const float*)d_in[6];
    const float* W2       = (const float*)d_in[7];
    const float* Wp       = (const float*)d_in[8];
    const float* bp       = (const float*)d_in[9];
    const int*   src      = (const int*)d_in[10];
    const int*   dst      = (const int*)d_in[11];
    float* out = (float*)d_out;

    char* ws = (char*)d_ws;
    size_t off = 0;
    auto alloc = [&](size_t bytes) { size_t o = off; off = (off + bytes + 255) & ~(size_t)255; return o; };
    half_t* Hb      = (half_t*)(ws + alloc((size_t)MM * NN * 256 * 2));
    half_t* feat    = (half_t*)(ws + alloc((size_t)MM * NN * 256 * 2));
    float*  P       = (float*)(ws + alloc((size_t)MM * NN * 64 * 4));
    float*  el      = (float*)(ws + alloc((size_t)MM * NN * 4 * 4));
    float*  er      = (float*)(ws + alloc((size_t)MM * NN * 4 * 4));
    int*    counts  = (int*)(ws + alloc((size_t)MM * NN * 4));
    int*    row_ptr = (int*)(ws + alloc((size_t)MM * (NN + 1) * 4));
    int*    cursor  = (int*)(ws + alloc((size_t)MM * (NN + 1) * 4));
    long long* spair = (long long*)(ws + alloc((size_t)MM * EE * 8));
    int*    bsum    = (int*)(ws + alloc((size_t)MM * NCHUNK * 4));
    short*  Whi     = (short*)(ws + alloc((size_t)W_TOT * 2));
    short*  Wlo     = (short*)(ws + alloc((size_t)W_TOT * 2));
    float*  wsum    = (float*)(ws + alloc(16));

    const int histBlocks = (EE + 255) / 256;       // 1563

    init_kernel<<<dim3((MM * NN + 255) / 256), 256, 0, stream>>>(counts, wsum);
    hist_splitW_kernel<<<dim3(histBlocks + SPLITW_PER_Y, MM), 256, 0, stream>>>(
        dst, counts, W_gat, W1, Wp, Whi, Wlo, histBlocks);
    scan_partial_kernel<<<dim3(NCHUNK, MM), 256, 0, stream>>>(counts, row_ptr, bsum);
    scan_top_kernel<<<dim3(1), 256, 0, stream>>>(bsum);
    scan_add_kernel<<<dim3(NCHUNK, MM), 256, 0, stream>>>(bsum, row_ptr, cursor);

    const int rowTiles = (NN + 63) / 64;           // 782

    // layer 0: fused GEMM<0> + scatter (independent work, co-dispatched)
    gemm0_scatter_kernel<<<dim3(rowTiles + histBlocks, MM), 256, 0, stream>>>(
        x, Whi, Wlo, feat, attn_l, attn_r, el, er,
        src, dst, cursor, spair, rowTiles);
    agg_edges_kernel<<<dim3(NN / 4, MM), 256, 0, stream>>>(
        feat, el, er, row_ptr, spair, bias_gat, Hb);

    // layer 1
    mfma_gemm1_kernel<<<dim3(rowTiles, MM), 256, 0, stream>>>(
        Hb, Whi + (size_t)MM * 65536, Wlo + (size_t)MM * 65536,
        feat, attn_l + (size_t)MM * 256, attn_r + (size_t)MM * 256, el, er);
    agg_edges_kernel<<<dim3(NN / 4, MM), 256, 0, stream>>>(
        feat, el, er, row_ptr, spair, bias_gat + (size_t)MM * 256, Hb);

    // merged semantic + projection pass over all 3 metapaths (Hb contiguous)
    sem_gemm<<<dim3((MM * NN + 127) / 128), 256, 0, stream>>>(
        Hb, Whi + WG_ELEMS, Wlo + WG_ELEMS, P, b1, W2, wsum, MM * NN);
    combine_out_kernel<<<dim3((NN * 16 + 255) / 256), 256, 0, stream>>>(P, wsum, bp, out);
}